// Round 2
// baseline (212.834 us; speedup 1.0000x reference)
//
#include <hip/hip_runtime.h>

// EdgeLoss: weighted BCE-with-logits mean over 32x1x768x1024 fp32 tensors.
// result = (neg_num * S_pos + pos_num * S_neg) / (pos_num + neg_num) / n
// S_pos = sum over t==1 of bce(x,1), S_neg = sum over t==0 of bce(x,0),
// bce(x,t) = max(x,0) - x*t + log(1+exp(-|x|)).
//
// R13 -> R14: revert dual-path split (R13 proved L3-hit path ~1.6 TB/s,
// slower than NT-HBM; FETCH halved as predicted but loop serialized at
// the slow path). Back to NT-both, PLUS the one untried combination:
// register-batched NT loads (BATCH=4 per stream, stream-grouped). Each
// wave issues 4 consecutive x-loads (16 KB contiguous burst), then 4
// t-loads, then computes 16 elements -- 8 NT loads in flight per wave
// and page-friendly per-stream bursts instead of x,t,x,t alternation.
// (R5's reg-batch was pre-NT; this tests reg-batch x NT.)
// Predict: stage1 55 -> 43-48 us if MLP/page-grouping was the limiter;
// neutral if 3.66 TB/s is the NT-read ceiling (then R12 is roofline).

#define GRID1 2048
#define BLOCK 256
#define BATCH 4
#define NACC 5

typedef float floatx4 __attribute__((ext_vector_type(4)));

__device__ __forceinline__ void do_elem(float xv, float tv,
                                        float& cnt_all, float& cnt_pos,
                                        float& sum_c, float& sum_tc,
                                        float& sum_tx) {
  float a = fabsf(xv);
  float e = __expf(-a);                  // v_exp_f32
  float l = __logf(1.0f + e);            // v_log_f32
  float c = fmaxf(xv, 0.f) + l;          // softplus(x): bce(t=0)=c, bce(t=1)=c-x
  bool valid = (tv < 1.5f);              // t in {0,1}
  float tm = valid ? tv : 0.0f;          // 1 for pos, 0 otherwise (t exact)
  cnt_all += valid ? 1.0f : 0.0f;
  cnt_pos += tm;
  sum_c   += valid ? c : 0.0f;
  sum_tc   = fmaf(tm, c, sum_tc);
  sum_tx   = fmaf(tm, xv, sum_tx);
}

__device__ __forceinline__ void do_vec4(floatx4 xv, floatx4 tv,
                                        float& a0, float& a1, float& a2,
                                        float& a3, float& a4) {
  do_elem(xv.x, tv.x, a0, a1, a2, a3, a4);
  do_elem(xv.y, tv.y, a0, a1, a2, a3, a4);
  do_elem(xv.z, tv.z, a0, a1, a2, a3, a4);
  do_elem(xv.w, tv.w, a0, a1, a2, a3, a4);
}

__global__ __launch_bounds__(BLOCK, 8) void edge_loss_stage1(
    const float* __restrict__ x, const float* __restrict__ t,
    float* __restrict__ partials, long long n) {
  long long n4 = n >> 2;
  // Contiguous per-block segment [beg, end): 2048 independent sequential
  // DRAM streams.
  long long per = (n4 + gridDim.x - 1) / gridDim.x;
  long long beg = (long long)blockIdx.x * per;
  long long end = beg + per < n4 ? beg + per : n4;

  const floatx4* __restrict__ x4 = (const floatx4*)x;
  const floatx4* __restrict__ t4 = (const floatx4*)t;

  float a0 = 0.f, a1 = 0.f, a2 = 0.f, a3 = 0.f, a4 = 0.f;

  long long i = beg + threadIdx.x;
  // Batched main loop: BATCH NT loads from x (16 KB contiguous burst per
  // wave), then BATCH from t, then compute. 8 loads in flight per wave.
  for (; i + (long long)(BATCH - 1) * BLOCK < end; i += (long long)BATCH * BLOCK) {
    floatx4 xv[BATCH], tv[BATCH];
    #pragma unroll
    for (int b = 0; b < BATCH; ++b)
      xv[b] = __builtin_nontemporal_load(&x4[i + (long long)b * BLOCK]);
    #pragma unroll
    for (int b = 0; b < BATCH; ++b)
      tv[b] = __builtin_nontemporal_load(&t4[i + (long long)b * BLOCK]);
    #pragma unroll
    for (int b = 0; b < BATCH; ++b)
      do_vec4(xv[b], tv[b], a0, a1, a2, a3, a4);
  }
  // leftover vec4s in this block's segment
  for (; i < end; i += BLOCK) {
    floatx4 xv = __builtin_nontemporal_load(&x4[i]);
    floatx4 tv = __builtin_nontemporal_load(&t4[i]);
    do_vec4(xv, tv, a0, a1, a2, a3, a4);
  }
  // scalar tail (n not a multiple of 4), grid-stride across all blocks
  for (long long j = (n4 << 2) + (long long)blockIdx.x * BLOCK + threadIdx.x;
       j < n; j += (long long)gridDim.x * BLOCK) {
    do_elem(x[j], t[j], a0, a1, a2, a3, a4);
  }

  // wave-64 shuffle reduction
  #pragma unroll
  for (int off = 32; off > 0; off >>= 1) {
    a0 += __shfl_down(a0, off, 64);
    a1 += __shfl_down(a1, off, 64);
    a2 += __shfl_down(a2, off, 64);
    a3 += __shfl_down(a3, off, 64);
    a4 += __shfl_down(a4, off, 64);
  }

  __shared__ float s_acc[4][NACC];
  int lane = threadIdx.x & 63;
  int wave = threadIdx.x >> 6;
  if (lane == 0) {
    s_acc[wave][0] = a0; s_acc[wave][1] = a1; s_acc[wave][2] = a2;
    s_acc[wave][3] = a3; s_acc[wave][4] = a4;
  }
  __syncthreads();
  if (threadIdx.x == 0) {
    float r[NACC] = {0.f, 0.f, 0.f, 0.f, 0.f};
    #pragma unroll
    for (int w = 0; w < 4; ++w)
      #pragma unroll
      for (int c = 0; c < NACC; ++c) r[c] += s_acc[w][c];
    int G = gridDim.x;
    #pragma unroll
    for (int c = 0; c < NACC; ++c) partials[c * G + blockIdx.x] = r[c];
  }
}

__global__ __launch_bounds__(BLOCK) void edge_loss_stage2(
    const float* __restrict__ partials, float* __restrict__ out,
    int G, double inv_n) {
  double acc[NACC] = {0.0, 0.0, 0.0, 0.0, 0.0};
  for (int i = threadIdx.x; i < G; i += BLOCK) {
    #pragma unroll
    for (int c = 0; c < NACC; ++c) acc[c] += (double)partials[c * G + i];
  }
  #pragma unroll
  for (int off = 32; off > 0; off >>= 1) {
    #pragma unroll
    for (int c = 0; c < NACC; ++c) acc[c] += __shfl_down(acc[c], off, 64);
  }
  __shared__ double s_acc[4][NACC];
  int lane = threadIdx.x & 63;
  int wave = threadIdx.x >> 6;
  if (lane == 0) {
    #pragma unroll
    for (int c = 0; c < NACC; ++c) s_acc[wave][c] = acc[c];
  }
  __syncthreads();
  if (threadIdx.x == 0) {
    double r[NACC] = {0.0, 0.0, 0.0, 0.0, 0.0};
    #pragma unroll
    for (int w = 0; w < 4; ++w)
      #pragma unroll
      for (int c = 0; c < NACC; ++c) r[c] += s_acc[w][c];
    double pos  = r[1];
    double neg  = r[0] - r[1];
    double spos = r[3] - r[4];        // sum_tc - sum_tx
    double sneg = r[2] - r[3];        // sum_c  - sum_tc
    double s = pos + neg;
    out[0] = (float)((neg * spos + pos * sneg) / s * inv_n);
  }
}

extern "C" void kernel_launch(void* const* d_in, const int* in_sizes, int n_in,
                              void* d_out, int out_size, void* d_ws, size_t ws_size,
                              hipStream_t stream) {
  const float* x = (const float*)d_in[0];
  const float* t = (const float*)d_in[1];
  long long n = (long long)in_sizes[0];
  float* partials = (float*)d_ws;  // NACC * GRID1 floats = 40 KB, fully written

  edge_loss_stage1<<<GRID1, BLOCK, 0, stream>>>(x, t, partials, n);
  edge_loss_stage2<<<1, BLOCK, 0, stream>>>(partials, (float*)d_out,
                                            GRID1, 1.0 / (double)n);
}

// Round 3
// 198.798 us; speedup vs baseline: 1.0706x; 1.0706x over previous
//
#include <hip/hip_runtime.h>

// EdgeLoss: weighted BCE-with-logits mean over 32x1x768x1024 fp32 tensors.
// result = (neg_num * S_pos + pos_num * S_neg) / (pos_num + neg_num) / n
// S_pos = sum over t==1 of bce(x,1), S_neg = sum over t==0 of bce(x,0),
// bce(x,t) = max(x,0) - x*t + log(1+exp(-|x|)).
//
// R14 -> R15: grid-stride coalesced mapping (one variable vs R12).
// Evidence so far: NT-both at 3.66 TB/s; L3 path slower (R13); deeper
// per-wave MLP neutral (R14). Remaining suspect: the per-block-segment
// decomposition = 4096 concurrent sequential streams (2048 blocks x 2
// buffers), ~30+ open-row streams per HBM pseudo-channel -> row thrash.
// Grid-stride gives the whole device ONE compact ~8 MB moving front per
// buffer (the same mapping fillBuffer/copy kernels use at 6.3-6.8 TB/s).
// Predict: stage1 55 -> 40-47 us (fetch BW 3.66 -> 4.5-5 TB/s) if row
// locality was the limiter; neutral -> NT ceiling confirmed, revert R12
// and declare roofline.

#define GRID1 2048
#define BLOCK 256
#define NACC 5

typedef float floatx4 __attribute__((ext_vector_type(4)));

__device__ __forceinline__ void do_elem(float xv, float tv,
                                        float& cnt_all, float& cnt_pos,
                                        float& sum_c, float& sum_tc,
                                        float& sum_tx) {
  float a = fabsf(xv);
  float e = __expf(-a);                  // v_exp_f32
  float l = __logf(1.0f + e);            // v_log_f32
  float c = fmaxf(xv, 0.f) + l;          // softplus(x): bce(t=0)=c, bce(t=1)=c-x
  bool valid = (tv < 1.5f);              // t in {0,1}
  float tm = valid ? tv : 0.0f;          // 1 for pos, 0 otherwise (t exact)
  cnt_all += valid ? 1.0f : 0.0f;
  cnt_pos += tm;
  sum_c   += valid ? c : 0.0f;
  sum_tc   = fmaf(tm, c, sum_tc);
  sum_tx   = fmaf(tm, xv, sum_tx);
}

__device__ __forceinline__ void do_vec4(floatx4 xv, floatx4 tv,
                                        float& a0, float& a1, float& a2,
                                        float& a3, float& a4) {
  do_elem(xv.x, tv.x, a0, a1, a2, a3, a4);
  do_elem(xv.y, tv.y, a0, a1, a2, a3, a4);
  do_elem(xv.z, tv.z, a0, a1, a2, a3, a4);
  do_elem(xv.w, tv.w, a0, a1, a2, a3, a4);
}

__global__ __launch_bounds__(BLOCK, 8) void edge_loss_stage1(
    const float* __restrict__ x, const float* __restrict__ t,
    float* __restrict__ partials, long long n) {
  long long n4 = n >> 2;

  const floatx4* __restrict__ x4 = (const floatx4*)x;
  const floatx4* __restrict__ t4 = (const floatx4*)t;

  float a0 = 0.f, a1 = 0.f, a2 = 0.f, a3 = 0.f, a4 = 0.f;

  // Grid-stride: whole device advances one compact front through each
  // buffer (8 MB window per step), maximizing DRAM row-buffer hits.
  long long stride = (long long)gridDim.x * BLOCK;
  #pragma unroll 2
  for (long long i = (long long)blockIdx.x * BLOCK + threadIdx.x;
       i < n4; i += stride) {
    floatx4 xv = __builtin_nontemporal_load(&x4[i]);
    floatx4 tv = __builtin_nontemporal_load(&t4[i]);
    do_vec4(xv, tv, a0, a1, a2, a3, a4);
  }
  // scalar tail (n not a multiple of 4), grid-stride across all blocks
  for (long long j = (n4 << 2) + (long long)blockIdx.x * BLOCK + threadIdx.x;
       j < n; j += stride) {
    do_elem(x[j], t[j], a0, a1, a2, a3, a4);
  }

  // wave-64 shuffle reduction
  #pragma unroll
  for (int off = 32; off > 0; off >>= 1) {
    a0 += __shfl_down(a0, off, 64);
    a1 += __shfl_down(a1, off, 64);
    a2 += __shfl_down(a2, off, 64);
    a3 += __shfl_down(a3, off, 64);
    a4 += __shfl_down(a4, off, 64);
  }

  __shared__ float s_acc[4][NACC];
  int lane = threadIdx.x & 63;
  int wave = threadIdx.x >> 6;
  if (lane == 0) {
    s_acc[wave][0] = a0; s_acc[wave][1] = a1; s_acc[wave][2] = a2;
    s_acc[wave][3] = a3; s_acc[wave][4] = a4;
  }
  __syncthreads();
  if (threadIdx.x == 0) {
    float r[NACC] = {0.f, 0.f, 0.f, 0.f, 0.f};
    #pragma unroll
    for (int w = 0; w < 4; ++w)
      #pragma unroll
      for (int c = 0; c < NACC; ++c) r[c] += s_acc[w][c];
    int G = gridDim.x;
    #pragma unroll
    for (int c = 0; c < NACC; ++c) partials[c * G + blockIdx.x] = r[c];
  }
}

__global__ __launch_bounds__(BLOCK) void edge_loss_stage2(
    const float* __restrict__ partials, float* __restrict__ out,
    int G, double inv_n) {
  double acc[NACC] = {0.0, 0.0, 0.0, 0.0, 0.0};
  for (int i = threadIdx.x; i < G; i += BLOCK) {
    #pragma unroll
    for (int c = 0; c < NACC; ++c) acc[c] += (double)partials[c * G + i];
  }
  #pragma unroll
  for (int off = 32; off > 0; off >>= 1) {
    #pragma unroll
    for (int c = 0; c < NACC; ++c) acc[c] += __shfl_down(acc[c], off, 64);
  }
  __shared__ double s_acc[4][NACC];
  int lane = threadIdx.x & 63;
  int wave = threadIdx.x >> 6;
  if (lane == 0) {
    #pragma unroll
    for (int c = 0; c < NACC; ++c) s_acc[wave][c] = acc[c];
  }
  __syncthreads();
  if (threadIdx.x == 0) {
    double r[NACC] = {0.0, 0.0, 0.0, 0.0, 0.0};
    #pragma unroll
    for (int w = 0; w < 4; ++w)
      #pragma unroll
      for (int c = 0; c < NACC; ++c) r[c] += s_acc[w][c];
    double pos  = r[1];
    double neg  = r[0] - r[1];
    double spos = r[3] - r[4];        // sum_tc - sum_tx
    double sneg = r[2] - r[3];        // sum_c  - sum_tc
    double s = pos + neg;
    out[0] = (float)((neg * spos + pos * sneg) / s * inv_n);
  }
}

extern "C" void kernel_launch(void* const* d_in, const int* in_sizes, int n_in,
                              void* d_out, int out_size, void* d_ws, size_t ws_size,
                              hipStream_t stream) {
  const float* x = (const float*)d_in[0];
  const float* t = (const float*)d_in[1];
  long long n = (long long)in_sizes[0];
  float* partials = (float*)d_ws;  // NACC * GRID1 floats = 40 KB, fully written

  edge_loss_stage1<<<GRID1, BLOCK, 0, stream>>>(x, t, partials, n);
  edge_loss_stage2<<<1, BLOCK, 0, stream>>>(partials, (float*)d_out,
                                            GRID1, 1.0 / (double)n);
}